// Round 2
// baseline (3162.877 us; speedup 1.0000x reference)
//
#include <hip/hip_runtime.h>
#include <stdint.h>
#include <math.h>

// Problem constants (fixed by setup_inputs)
#define H_IMG 256
#define W_IMG 128
#define LTOK  32768
#define BATCH 4
#define CDIM  256
#define HIDDIM 1024
#define NHEAD 8
#define HD    32
#define MROWS 131072   // B * L
#define FCH   128      // LeFF channel chunk (8 chunks of 128)

// ---------- helpers ----------
__device__ __forceinline__ float bf2f(unsigned u) {
  union { unsigned u; float f; } c; c.u = u << 16; return c.f;
}
__device__ __forceinline__ unsigned short f2bf(float f) {
  union { float f; unsigned u; } c; c.f = f;
  unsigned r = c.u + 0x7fffu + ((c.u >> 16) & 1u);  // RNE
  return (unsigned short)(r >> 16);
}
__device__ __forceinline__ void unpack8(uint4 t, float* dst) {
  dst[0] = bf2f(t.x & 0xffffu); dst[1] = bf2f(t.x >> 16);
  dst[2] = bf2f(t.y & 0xffffu); dst[3] = bf2f(t.y >> 16);
  dst[4] = bf2f(t.z & 0xffffu); dst[5] = bf2f(t.z >> 16);
  dst[6] = bf2f(t.w & 0xffffu); dst[7] = bf2f(t.w >> 16);
}
__device__ __forceinline__ float gelu_f(float x) {
  return 0.5f * x * (1.0f + erff(x * 0.70710678118654752f));
}

// ---------- LayerNorm (fp32 in -> bf16 out), one wave per row of C=256 ----------
__global__ __launch_bounds__(256) void ln_kernel(
    const float* __restrict__ x, const float* __restrict__ g,
    const float* __restrict__ b, unsigned short* __restrict__ out) {
  const int wave = threadIdx.x >> 6;
  const int lane = threadIdx.x & 63;
  const size_t row = (size_t)blockIdx.x * 4 + wave;
  float4 f = ((const float4*)(x + row * CDIM))[lane];
  float s  = f.x + f.y + f.z + f.w;
  float sq = f.x*f.x + f.y*f.y + f.z*f.z + f.w*f.w;
#pragma unroll
  for (int o = 32; o > 0; o >>= 1) { s += __shfl_down(s, o); sq += __shfl_down(sq, o); }
  s = __shfl(s, 0); sq = __shfl(sq, 0);
  const float mu = s * (1.0f / CDIM);
  const float var = sq * (1.0f / CDIM) - mu * mu;
  const float rstd = rsqrtf(var + 1e-5f);
  float4 gg = ((const float4*)g)[lane];
  float4 bb = ((const float4*)b)[lane];
  unsigned short o4[4];
  o4[0] = f2bf((f.x - mu) * rstd * gg.x + bb.x);
  o4[1] = f2bf((f.y - mu) * rstd * gg.y + bb.y);
  o4[2] = f2bf((f.z - mu) * rstd * gg.z + bb.z);
  o4[3] = f2bf((f.w - mu) * rstd * gg.w + bb.w);
  *(uint2*)(out + row * CDIM + lane * 4) = *(uint2*)o4;
}

// ---------- Tiled GEMM: out[M,:] = A[M,K](bf16) @ B[K, view](f32) + bias*bscale ----------
// B is a column-view with row stride ldb; out/res have row stride ldc.
// EPI 0: out bf16 = acc + bias*bscale
// EPI 1: out f32  = acc + bias*bscale + res   (res may alias out; same-thread RMW)
// EPI 2: out bf16 = gelu(acc + bias*bscale)
// BM=128, BN=128 (grid.y = ldc/128), BK=16, 256 threads, 8x8 per thread.
template<int EPI>
__global__ __launch_bounds__(256, 2) void gemm128(
    const unsigned short* __restrict__ A, const float* __restrict__ B,
    const float* __restrict__ bias, float bscale, const float* __restrict__ res,
    void* __restrict__ outp, int K, int ldb, int ldc) {
  __shared__ float As[16][132];  // [k][m], padded
  __shared__ float Bs[16][132];  // [k][n], padded
  const int tid = threadIdx.x;
  const int tx = tid & 15, ty = tid >> 4;
  const int m0 = blockIdx.x * 128, n0 = blockIdx.y * 128;
  const int arow = tid >> 1, ac8 = (tid & 1) * 8;   // A tile: 128 rows x 16 k
  const int brow = tid >> 4, bc4 = (tid & 15) * 4;  // B tile: 16 k x 128 n
  float acc[8][8] = {};
  for (int kk = 0; kk < K; kk += 16) {
    uint4 av = *(const uint4*)(A + (size_t)(m0 + arow) * K + kk + ac8);
    float af[8]; unpack8(av, af);
#pragma unroll
    for (int i2 = 0; i2 < 8; ++i2) As[ac8 + i2][arow] = af[i2];
    const float* bp = B + (size_t)(kk + brow) * ldb + n0 + bc4;
    float4 b0 = *(const float4*)bp;
    float4 b1 = *(const float4*)(bp + 64);
    *(float4*)&Bs[brow][bc4]      = b0;
    *(float4*)&Bs[brow][bc4 + 64] = b1;
    __syncthreads();
#pragma unroll
    for (int k = 0; k < 16; ++k) {
      float a[8], bb[8];
      *(float4*)&a[0]  = *(const float4*)&As[k][ty * 8];
      *(float4*)&a[4]  = *(const float4*)&As[k][ty * 8 + 4];
      *(float4*)&bb[0] = *(const float4*)&Bs[k][tx * 8];
      *(float4*)&bb[4] = *(const float4*)&Bs[k][tx * 8 + 4];
#pragma unroll
      for (int i2 = 0; i2 < 8; ++i2)
#pragma unroll
        for (int j2 = 0; j2 < 8; ++j2)
          acc[i2][j2] += a[i2] * bb[j2];
    }
    __syncthreads();
  }
  const int gm = m0 + ty * 8, gn = n0 + tx * 8;
  float bb[8];
  *(float4*)&bb[0] = *(const float4*)(bias + gn);
  *(float4*)&bb[4] = *(const float4*)(bias + gn + 4);
#pragma unroll
  for (int i2 = 0; i2 < 8; ++i2) {
    const size_t row = (size_t)(gm + i2);
    float vals[8];
#pragma unroll
    for (int j2 = 0; j2 < 8; ++j2) vals[j2] = acc[i2][j2] + bb[j2] * bscale;
    if (EPI == 1) {
      float r[8];
      *(float4*)&r[0] = *(const float4*)(res + row * ldc + gn);
      *(float4*)&r[4] = *(const float4*)(res + row * ldc + gn + 4);
#pragma unroll
      for (int j2 = 0; j2 < 8; ++j2) vals[j2] += r[j2];
    }
    if (EPI == 2) {
#pragma unroll
      for (int j2 = 0; j2 < 8; ++j2) vals[j2] = gelu_f(vals[j2]);
    }
    if (EPI == 1) {
      float* o = (float*)outp + row * ldc + gn;
      *(float4*)o       = *(float4*)&vals[0];
      *(float4*)(o + 4) = *(float4*)&vals[4];
    } else {
      unsigned short ov[8];
#pragma unroll
      for (int j2 = 0; j2 < 8; ++j2) ov[j2] = f2bf(vals[j2]);
      *(uint4*)((unsigned short*)outp + row * ldc + gn) = *(uint4*)ov;
    }
  }
}

// ---------- Window attention (k = q shared), one wave per (window, head) ----------
// Roll folded into gather/scatter: rolled pos p reads & writes original pos
// (p + off) mod (H,W). Shift-mask regions computed from rolled coords.
__global__ __launch_bounds__(64) void attn_kernel(
    const unsigned short* __restrict__ q, const unsigned short* __restrict__ v,
    const float* __restrict__ rpb, const int* __restrict__ pHo,
    const int* __restrict__ pWo, unsigned short* __restrict__ yout) {
  __shared__ float qs[64][33];
  __shared__ float vs[64][33];
  __shared__ float bias_s[225];
  __shared__ int reg_s[64];
  const int lane = threadIdx.x;
  const int hh = blockIdx.y;
  const int wb = blockIdx.x;          // b*512 + wh*16 + ww
  const int b = wb >> 9, wloc = wb & 511;
  const int wh = wloc >> 4, ww = wloc & 15;
  const int Ho = pHo[0], Wo = pWo[0];
  const int dy = lane >> 3, dx = lane & 7;
  const int hr = wh * 8 + dy, wr = ww * 8 + dx;   // rolled coords
  int ho = hr + Ho; if (ho >= H_IMG) ho -= H_IMG; // original coords
  int wo = wr + Wo; if (wo >= W_IMG) wo -= W_IMG;
  const size_t base = ((size_t)b * LTOK + (size_t)ho * W_IMG + wo) * CDIM + hh * HD;

  float qr[32];
  const uint4* qp = (const uint4*)(q + base);
  const uint4* vp = (const uint4*)(v + base);
#pragma unroll
  for (int u = 0; u < 4; ++u) {
    float f8[8];
    unpack8(qp[u], f8);
#pragma unroll
    for (int e = 0; e < 8; ++e) { qr[u * 8 + e] = f8[e]; qs[lane][u * 8 + e] = f8[e]; }
    unpack8(vp[u], f8);
#pragma unroll
    for (int e = 0; e < 8; ++e) vs[lane][u * 8 + e] = f8[e];
  }
  // shift-mask region id
  const int rh = (hr < H_IMG - 8) ? 0 : ((hr < H_IMG - Ho) ? 1 : 2);
  const int rw = (wr < W_IMG - 8) ? 0 : ((wr < W_IMG - Wo) ? 1 : 2);
  reg_s[lane] = rh * 3 + rw;
  for (int i = lane; i < 225; i += 64) bias_s[i] = rpb[i * 8 + hh];
  __syncthreads();

  const float scale = 0.17677669529663687f;  // 32^-0.5
#pragma unroll
  for (int k2 = 0; k2 < 32; ++k2) qr[k2] *= scale;

  float p[64];
  float mx = -3.0e38f;
  const int myreg = reg_s[lane];
#pragma unroll
  for (int j = 0; j < 64; ++j) {
    float s = 0.0f;
#pragma unroll
    for (int k2 = 0; k2 < 32; ++k2) s += qr[k2] * qs[j][k2];
    const int rel = (dy - (j >> 3) + 7) * 15 + (dx - (j & 7) + 7);
    s += bias_s[rel];
    if (reg_s[j] != myreg) s -= 100.0f;
    p[j] = s;
    mx = fmaxf(mx, s);
  }
  float sum = 0.0f;
#pragma unroll
  for (int j = 0; j < 64; ++j) { float e = __expf(p[j] - mx); p[j] = e; sum += e; }
  const float inv = 1.0f / sum;
  float acc[32] = {};
#pragma unroll
  for (int j = 0; j < 64; ++j) {
    const float pj = p[j] * inv;
#pragma unroll
    for (int k2 = 0; k2 < 32; ++k2) acc[k2] += pj * vs[j][k2];
  }
  unsigned short o[32];
#pragma unroll
  for (int k2 = 0; k2 < 32; ++k2) o[k2] = f2bf(acc[k2]);
  uint4* op = (uint4*)(yout + base);
#pragma unroll
  for (int u = 0; u < 4; ++u) op[u] = ((uint4*)o)[u];
}

// ---------- Depthwise 3x3 conv (chunk of FCH=128 channels, SAME, zero pad) + GELU ----------
// t/out: [131072 tokens, 128 ch] bf16. 32 lanes per token, 8 tokens per block.
__global__ __launch_bounds__(256) void dwconv_kernel(
    const unsigned short* __restrict__ t, const float* __restrict__ k9,
    const float* __restrict__ bias, unsigned short* __restrict__ out) {
  const int c = (threadIdx.x & 31) * 4;
  const int token = blockIdx.x * 8 + (threadIdx.x >> 5);
  float wreg[4][9];
#pragma unroll
  for (int j = 0; j < 4; ++j)
#pragma unroll
    for (int tp = 0; tp < 9; ++tp) wreg[j][tp] = k9[(c + j) * 9 + tp];
  const float4 bv = *(const float4*)(bias + c);
  const int b = token >> 15, l0 = token & (LTOK - 1);
  const int h = l0 >> 7, w = l0 & 127;
  float a0 = 0, a1 = 0, a2 = 0, a3 = 0;
#pragma unroll
  for (int ky = 0; ky < 3; ++ky) {
    const int hy = h + ky - 1;
    if ((unsigned)hy >= (unsigned)H_IMG) continue;
#pragma unroll
    for (int kx = 0; kx < 3; ++kx) {
      const int wx = w + kx - 1;
      if ((unsigned)wx >= (unsigned)W_IMG) continue;
      const ushort4 tv = *(const ushort4*)(
          t + (((size_t)b * LTOK + (size_t)hy * W_IMG + wx) * FCH + c));
      const int tp = ky * 3 + kx;
      a0 += bf2f(tv.x) * wreg[0][tp];
      a1 += bf2f(tv.y) * wreg[1][tp];
      a2 += bf2f(tv.z) * wreg[2][tp];
      a3 += bf2f(tv.w) * wreg[3][tp];
    }
  }
  a0 = gelu_f(a0 + bv.x); a1 = gelu_f(a1 + bv.y);
  a2 = gelu_f(a2 + bv.z); a3 = gelu_f(a3 + bv.w);
  unsigned short o[4] = { f2bf(a0), f2bf(a1), f2bf(a2), f2bf(a3) };
  *(uint2*)(out + (size_t)token * FCH + c) = *(uint2*)o;
}

// ---------- launch ----------
extern "C" void kernel_launch(void* const* d_in, const int* in_sizes, int n_in,
                              void* d_out, int out_size, void* d_ws, size_t ws_size,
                              hipStream_t stream) {
  (void)in_sizes; (void)n_in; (void)out_size; (void)ws_size;
  const float* x     = (const float*)d_in[0];
  const float* n1g   = (const float*)d_in[1];
  const float* n1b   = (const float*)d_in[2];
  const float* wq    = (const float*)d_in[3];
  const float* bq    = (const float*)d_in[4];
  const float* wv    = (const float*)d_in[5];
  const float* bv    = (const float*)d_in[6];
  const float* rpb   = (const float*)d_in[7];
  const float* wproj = (const float*)d_in[8];
  const float* bproj = (const float*)d_in[9];
  const float* n2g   = (const float*)d_in[10];
  const float* n2b   = (const float*)d_in[11];
  const float* w1    = (const float*)d_in[12];
  const float* b1    = (const float*)d_in[13];
  const float* dwk   = (const float*)d_in[14];
  const float* dwb   = (const float*)d_in[15];
  const float* w2    = (const float*)d_in[16];
  const float* b2    = (const float*)d_in[17];
  const int*   pHo   = (const int*)d_in[18];
  const int*   pWo   = (const int*)d_in[19];
  float* out = (float*)d_out;

  // Scratch plan — peak ws usage 128 MiB total; d_out doubles as scratch:
  //   ws r0 [0, 64 MiB)   : bf16 131072x256  (xn -> yattn -> xn2)
  //   ws r1 [64, 128 MiB) : bf16 q (131072x256); later t1_chunk | t2_chunk
  //   d_out               : bf16 v (first 64 MiB)  -> f32 xattn -> final out
  char* wsb = (char*)d_ws;
  unsigned short* r0  = (unsigned short*)wsb;                  // xn / yattn / xn2
  unsigned short* qb  = (unsigned short*)(wsb + 67108864ull);  // q
  unsigned short* t1c = (unsigned short*)(wsb + 67108864ull);  // [131072,128] bf16
  unsigned short* t2c = (unsigned short*)(wsb + 100663296ull); // [131072,128] bf16
  unsigned short* vb  = (unsigned short*)d_out;                // v staged in d_out

  // 1. LN1: x -> xn (r0)
  ln_kernel<<<32768, 256, 0, stream>>>(x, n1g, n1b, r0);
  // 2. q = xn@wq + bq -> r1 (bf16)
  gemm128<0><<<dim3(1024, 2), 256, 0, stream>>>(r0, wq, bq, 1.0f, nullptr, qb, CDIM, CDIM, CDIM);
  // 3. v = xn@wv + bv -> d_out (bf16 scratch)
  gemm128<0><<<dim3(1024, 2), 256, 0, stream>>>(r0, wv, bv, 1.0f, nullptr, vb, CDIM, CDIM, CDIM);
  // 4. window attention (k = q) -> yattn (r0; xn dead)
  attn_kernel<<<dim3(2048, NHEAD), 64, 0, stream>>>(qb, vb, rpb, pHo, pWo, r0);
  // 5. xattn = x + yattn@wproj + bproj -> d_out f32 (v dead)
  gemm128<1><<<dim3(1024, 2), 256, 0, stream>>>(r0, wproj, bproj, 1.0f, x, out, CDIM, CDIM, CDIM);
  // 6. LN2: d_out -> xn2 (r0; yattn dead)
  ln_kernel<<<32768, 256, 0, stream>>>(out, n2g, n2b, r0);
  // 7-9. LeFF in 8 chunks of 128 hidden channels (depthwise conv is channel-local;
  //      FF2 is split-K accumulated into d_out, bias b2 added only on chunk 0).
  for (int c = 0; c < 8; ++c) {
    gemm128<2><<<dim3(1024, 1), 256, 0, stream>>>(
        r0, w1 + c * FCH, b1 + c * FCH, 1.0f, nullptr, t1c, CDIM, HIDDIM, FCH);
    dwconv_kernel<<<16384, 256, 0, stream>>>(
        t1c, dwk + (size_t)c * FCH * 9, dwb + c * FCH, t2c);
    gemm128<1><<<dim3(1024, 2), 256, 0, stream>>>(
        t2c, w2 + (size_t)c * FCH * CDIM, b2, (c == 0) ? 1.0f : 0.0f,
        out, out, FCH, CDIM, CDIM);
  }
}

// Round 3
// 1961.866 us; speedup vs baseline: 1.6122x; 1.6122x over previous
//
#include <hip/hip_runtime.h>
#include <stdint.h>
#include <math.h>

// Problem constants (fixed by setup_inputs)
#define H_IMG 256
#define W_IMG 128
#define LTOK  32768
#define BATCH 4
#define CDIM  256
#define HIDDIM 1024
#define NHEAD 8
#define HD    32
#define MROWS 131072   // B * L

typedef __attribute__((ext_vector_type(8))) short short8;
typedef __attribute__((ext_vector_type(4))) float f32x4;

// ---------- helpers ----------
__device__ __forceinline__ float bf2f(unsigned u) {
  union { unsigned u; float f; } c; c.u = u << 16; return c.f;
}
__device__ __forceinline__ unsigned short f2bf(float f) {
  union { float f; unsigned u; } c; c.f = f;
  unsigned r = c.u + 0x7fffu + ((c.u >> 16) & 1u);  // RNE
  return (unsigned short)(r >> 16);
}
__device__ __forceinline__ void unpack8(uint4 t, float* dst) {
  dst[0] = bf2f(t.x & 0xffffu); dst[1] = bf2f(t.x >> 16);
  dst[2] = bf2f(t.y & 0xffffu); dst[3] = bf2f(t.y >> 16);
  dst[4] = bf2f(t.z & 0xffffu); dst[5] = bf2f(t.z >> 16);
  dst[6] = bf2f(t.w & 0xffffu); dst[7] = bf2f(t.w >> 16);
}
__device__ __forceinline__ float gelu_f(float x) {
  return 0.5f * x * (1.0f + erff(x * 0.70710678118654752f));
}
__device__ __forceinline__ void gload_lds16(const void* g, void* l) {
  __builtin_amdgcn_global_load_lds(
      (const __attribute__((address_space(1))) unsigned int*)g,
      (__attribute__((address_space(3))) unsigned int*)l, 16, 0, 0);
}

// ---------- weight convert: f32 [K,N] -> bf16 [N,K] (transpose) ----------
__global__ __launch_bounds__(256) void wconv_kernel(
    const float* __restrict__ w, unsigned short* __restrict__ wt, int K, int N) {
  __shared__ float t[32][33];
  const int k0 = blockIdx.x * 32, n0 = blockIdx.y * 32;
  const int tx = threadIdx.x & 31, ty = threadIdx.x >> 5;
#pragma unroll
  for (int i = 0; i < 4; ++i)
    t[ty + 8 * i][tx] = w[(size_t)(k0 + ty + 8 * i) * N + n0 + tx];
  __syncthreads();
#pragma unroll
  for (int i = 0; i < 4; ++i)
    wt[(size_t)(n0 + ty + 8 * i) * K + k0 + tx] = f2bf(t[tx][ty + 8 * i]);
}

// ---------- LayerNorm (fp32 in -> bf16 out), one wave per row of C=256 ----------
__global__ __launch_bounds__(256) void ln_kernel(
    const float* __restrict__ x, const float* __restrict__ g,
    const float* __restrict__ b, unsigned short* __restrict__ out) {
  const int wave = threadIdx.x >> 6;
  const int lane = threadIdx.x & 63;
  const size_t row = (size_t)blockIdx.x * 4 + wave;
  float4 f = ((const float4*)(x + row * CDIM))[lane];
  float s  = f.x + f.y + f.z + f.w;
  float sq = f.x*f.x + f.y*f.y + f.z*f.z + f.w*f.w;
#pragma unroll
  for (int o = 32; o > 0; o >>= 1) { s += __shfl_down(s, o); sq += __shfl_down(sq, o); }
  s = __shfl(s, 0); sq = __shfl(sq, 0);
  const float mu = s * (1.0f / CDIM);
  const float var = sq * (1.0f / CDIM) - mu * mu;
  const float rstd = rsqrtf(var + 1e-5f);
  float4 gg = ((const float4*)g)[lane];
  float4 bb = ((const float4*)b)[lane];
  unsigned short o4[4];
  o4[0] = f2bf((f.x - mu) * rstd * gg.x + bb.x);
  o4[1] = f2bf((f.y - mu) * rstd * gg.y + bb.y);
  o4[2] = f2bf((f.z - mu) * rstd * gg.z + bb.z);
  o4[3] = f2bf((f.w - mu) * rstd * gg.w + bb.w);
  *(uint2*)(out + row * CDIM + lane * 4) = *(uint2*)o4;
}

// ---------- MFMA GEMM: out[M,:] = A[M,K](bf16) @ Bt[N,K](bf16)^T + bias ----------
// Bt is pre-transposed weights (row n holds column n of W, k-contiguous).
// BM=BN=128, BK=32, 256 threads = 4 waves, each wave 64x64 via 4x4 mfma_16x16x32.
// LDS chunks XOR-swizzled by (row&3) so ds_read_b128 is 2-way (free).
// EPI 0: bf16 = acc+bias*bscale   EPI 1: f32 = acc+bias*bscale+res (res may alias)
// EPI 2: bf16 = gelu(acc+bias*bscale)
template<int EPI>
__global__ __launch_bounds__(256) void mgemm(
    const unsigned short* __restrict__ A, const unsigned short* __restrict__ Bt,
    const float* __restrict__ bias, float bscale, const float* __restrict__ res,
    void* __restrict__ outp, int K, int ldc) {
  __shared__ unsigned short As[128][32];
  __shared__ unsigned short Bs[128][32];
  const int tid = threadIdx.x;
  const int w = tid >> 6, lane = tid & 63;
  const int m0 = blockIdx.x * 128, n0 = blockIdx.y * 128;
  const int wm = (w & 1) * 64, wn = (w >> 1) * 64;
  const int srow = lane >> 2;                 // 0..15 within a 16-row chunk
  const int csrc = (lane & 3) ^ (srow & 3);   // swizzled source 16B-chunk
  f32x4 acc[4][4];
#pragma unroll
  for (int mi = 0; mi < 4; ++mi)
#pragma unroll
    for (int ni = 0; ni < 4; ++ni)
#pragma unroll
      for (int r = 0; r < 4; ++r) acc[mi][ni][r] = 0.0f;

  const int kg = lane >> 4, ml = lane & 15;
  for (int kk = 0; kk < K; kk += 32) {
#pragma unroll
    for (int i = 0; i < 2; ++i) {
      const int rl = w * 32 + i * 16 + srow;       // local row 0..127
      gload_lds16(A + (size_t)(m0 + rl) * K + kk + csrc * 8, &As[w * 32 + i * 16][0]);
      gload_lds16(Bt + (size_t)(n0 + rl) * K + kk + csrc * 8, &Bs[w * 32 + i * 16][0]);
    }
    __syncthreads();
    short8 af[4], bg[4];
#pragma unroll
    for (int mi = 0; mi < 4; ++mi) {
      const int r = wm + mi * 16 + ml;
      af[mi] = *(const short8*)&As[r][(kg ^ (r & 3)) * 8];
    }
#pragma unroll
    for (int ni = 0; ni < 4; ++ni) {
      const int r = wn + ni * 16 + ml;
      bg[ni] = *(const short8*)&Bs[r][(kg ^ (r & 3)) * 8];
    }
#pragma unroll
    for (int mi = 0; mi < 4; ++mi)
#pragma unroll
      for (int ni = 0; ni < 4; ++ni)
        acc[mi][ni] = __builtin_amdgcn_mfma_f32_16x16x32_bf16(af[mi], bg[ni], acc[mi][ni], 0, 0, 0);
    __syncthreads();
  }
  // epilogue: C/D layout col=lane&15, row=(lane>>4)*4+r
#pragma unroll
  for (int ni = 0; ni < 4; ++ni) {
    const int n = n0 + wn + ni * 16 + ml;
    const float bn = bias[n] * bscale;
#pragma unroll
    for (int mi = 0; mi < 4; ++mi) {
#pragma unroll
      for (int r = 0; r < 4; ++r) {
        const int m = m0 + wm + mi * 16 + kg * 4 + r;
        const size_t idx = (size_t)m * ldc + n;
        float val = acc[mi][ni][r] + bn;
        if (EPI == 1) {
          ((float*)outp)[idx] = val + res[idx];
        } else if (EPI == 2) {
          ((unsigned short*)outp)[idx] = f2bf(gelu_f(val));
        } else {
          ((unsigned short*)outp)[idx] = f2bf(val);
        }
      }
    }
  }
}

// ---------- Window attention (k = q shared), one wave per (window, head) ----------
// bf16 LDS staging (9.4 KB/wave -> ~2x occupancy vs f32). Roll folded into
// gather/scatter; shift-mask regions computed from rolled coords.
__global__ __launch_bounds__(64) void attn_kernel(
    const unsigned short* __restrict__ q, const unsigned short* __restrict__ v,
    const float* __restrict__ rpb, const int* __restrict__ pHo,
    const int* __restrict__ pWo, unsigned short* __restrict__ yout) {
  __shared__ unsigned short qs[64][32];
  __shared__ unsigned short vs[64][32];
  __shared__ float bias_s[225];
  __shared__ int reg_s[64];
  const int lane = threadIdx.x;
  const int hh = blockIdx.y;
  const int wb = blockIdx.x;          // b*512 + wh*16 + ww
  const int b = wb >> 9, wloc = wb & 511;
  const int wh = wloc >> 4, ww = wloc & 15;
  const int Ho = pHo[0], Wo = pWo[0];
  const int dy = lane >> 3, dx = lane & 7;
  const int hr = wh * 8 + dy, wr = ww * 8 + dx;   // rolled coords
  int ho = hr + Ho; if (ho >= H_IMG) ho -= H_IMG; // original coords
  int wo = wr + Wo; if (wo >= W_IMG) wo -= W_IMG;
  const size_t base = ((size_t)b * LTOK + (size_t)ho * W_IMG + wo) * CDIM + hh * HD;

  float qr[32];
  const uint4* qp = (const uint4*)(q + base);
  const uint4* vp = (const uint4*)(v + base);
#pragma unroll
  for (int u = 0; u < 4; ++u) {
    uint4 t = qp[u];
    *(uint4*)&qs[lane][u * 8] = t;
    unpack8(t, &qr[u * 8]);
    *(uint4*)&vs[lane][u * 8] = vp[u];
  }
  const int rh = (hr < H_IMG - 8) ? 0 : ((hr < H_IMG - Ho) ? 1 : 2);
  const int rw = (wr < W_IMG - 8) ? 0 : ((wr < W_IMG - Wo) ? 1 : 2);
  reg_s[lane] = rh * 3 + rw;
  for (int i = lane; i < 225; i += 64) bias_s[i] = rpb[i * 8 + hh];
  __syncthreads();

  const float scale = 0.17677669529663687f;  // 32^-0.5
#pragma unroll
  for (int k2 = 0; k2 < 32; ++k2) qr[k2] *= scale;

  float p[64];
  float mx = -3.0e38f;
  const int myreg = reg_s[lane];
#pragma unroll
  for (int j = 0; j < 64; ++j) {
    float s = 0.0f;
#pragma unroll
    for (int u = 0; u < 4; ++u) {
      float f8[8];
      unpack8(*(const uint4*)&qs[j][u * 8], f8);   // broadcast read
#pragma unroll
      for (int e = 0; e < 8; ++e) s += qr[u * 8 + e] * f8[e];
    }
    const int rel = (dy - (j >> 3) + 7) * 15 + (dx - (j & 7) + 7);
    s += bias_s[rel];
    if (reg_s[j] != myreg) s -= 100.0f;
    p[j] = s;
    mx = fmaxf(mx, s);
  }
  float sum = 0.0f;
#pragma unroll
  for (int j = 0; j < 64; ++j) { float e = __expf(p[j] - mx); p[j] = e; sum += e; }
  const float inv = 1.0f / sum;
  float acc[32] = {};
#pragma unroll
  for (int j = 0; j < 64; ++j) {
    const float pj = p[j] * inv;
#pragma unroll
    for (int u = 0; u < 4; ++u) {
      float f8[8];
      unpack8(*(const uint4*)&vs[j][u * 8], f8);
#pragma unroll
      for (int e = 0; e < 8; ++e) acc[u * 8 + e] += pj * f8[e];
    }
  }
  unsigned short o[32];
#pragma unroll
  for (int k2 = 0; k2 < 32; ++k2) o[k2] = f2bf(acc[k2]);
  uint4* op = (uint4*)(yout + base);
#pragma unroll
  for (int u = 0; u < 4; ++u) op[u] = ((uint4*)o)[u];
}

// ---------- Depthwise 3x3 conv on a row band (full 1024 ch) + GELU ----------
// t1b: [(band+2 rows)*128, 1024] bf16 where buffer row = image row - hr0 + 1.
// Block: 8 tokens x 128 channels (chunk = blockIdx.y).
__global__ __launch_bounds__(256) void dwconv_kernel(
    const unsigned short* __restrict__ t1b, const float* __restrict__ k9,
    const float* __restrict__ bias, unsigned short* __restrict__ t2b,
    int hr0, int band_rows) {
  const int c = blockIdx.y * 128 + (threadIdx.x & 31) * 4;
  const int tok = blockIdx.x * 8 + (threadIdx.x >> 5);   // 0..band_rows*128-1
  const int h = hr0 + (tok >> 7), wcol = tok & 127;
  float wreg[4][9];
#pragma unroll
  for (int j = 0; j < 4; ++j)
#pragma unroll
    for (int tp = 0; tp < 9; ++tp) wreg[j][tp] = k9[(c + j) * 9 + tp];
  const float4 bv = *(const float4*)(bias + c);
  float a0 = 0, a1 = 0, a2 = 0, a3 = 0;
#pragma unroll
  for (int ky = 0; ky < 3; ++ky) {
    const int hy = h + ky - 1;
    if ((unsigned)hy >= (unsigned)H_IMG) continue;
    const int brow = (tok >> 7) + ky;   // buffer row
#pragma unroll
    for (int kx = 0; kx < 3; ++kx) {
      const int wx = wcol + kx - 1;
      if ((unsigned)wx >= (unsigned)W_IMG) continue;
      const ushort4 tv = *(const ushort4*)(
          t1b + ((size_t)(brow * 128 + wx)) * HIDDIM + c);
      const int tp = ky * 3 + kx;
      a0 += bf2f(tv.x) * wreg[0][tp];
      a1 += bf2f(tv.y) * wreg[1][tp];
      a2 += bf2f(tv.z) * wreg[2][tp];
      a3 += bf2f(tv.w) * wreg[3][tp];
    }
  }
  a0 = gelu_f(a0 + bv.x); a1 = gelu_f(a1 + bv.y);
  a2 = gelu_f(a2 + bv.z); a3 = gelu_f(a3 + bv.w);
  unsigned short o[4] = { f2bf(a0), f2bf(a1), f2bf(a2), f2bf(a3) };
  *(uint2*)(t2b + (size_t)tok * HIDDIM + c) = *(uint2*)o;
}

// ---------- launch ----------
extern "C" void kernel_launch(void* const* d_in, const int* in_sizes, int n_in,
                              void* d_out, int out_size, void* d_ws, size_t ws_size,
                              hipStream_t stream) {
  (void)in_sizes; (void)n_in; (void)out_size; (void)ws_size;
  const float* x     = (const float*)d_in[0];
  const float* n1g   = (const float*)d_in[1];
  const float* n1b   = (const float*)d_in[2];
  const float* wq    = (const float*)d_in[3];
  const float* bq    = (const float*)d_in[4];
  const float* wv    = (const float*)d_in[5];
  const float* bv    = (const float*)d_in[6];
  const float* rpb   = (const float*)d_in[7];
  const float* wproj = (const float*)d_in[8];
  const float* bproj = (const float*)d_in[9];
  const float* n2g   = (const float*)d_in[10];
  const float* n2b   = (const float*)d_in[11];
  const float* w1    = (const float*)d_in[12];
  const float* b1    = (const float*)d_in[13];
  const float* dwk   = (const float*)d_in[14];
  const float* dwb   = (const float*)d_in[15];
  const float* w2    = (const float*)d_in[16];
  const float* b2    = (const float*)d_in[17];
  const int*   pHo   = (const int*)d_in[18];
  const int*   pWo   = (const int*)d_in[19];
  float* out = (float*)d_out;

  // ws layout (<= 120 MB):
  //   r0   [0, 64Mi)        bf16 131072x256 : xn -> yattn -> xn2
  //   wt   [64Mi, +1.44MB)  bf16 transposed weights (wq,wv,wproj,w1,w2)
  //   t1b  (98 rows)        bf16 98*128*1024
  //   t2b  (96 rows)        bf16 96*128*1024
  // d_out doubles as scratch: lower half = v bf16, upper half = q bf16,
  // then whole = xattn f32 (q/v dead), finally += FF2 per band.
  char* wsb = (char*)d_ws;
  unsigned short* r0     = (unsigned short*)wsb;
  unsigned short* wqt    = (unsigned short*)(wsb + 67108864ull);
  unsigned short* wvt    = (unsigned short*)(wsb + 67108864ull + 131072ull);
  unsigned short* wprojt = (unsigned short*)(wsb + 67108864ull + 262144ull);
  unsigned short* w1t    = (unsigned short*)(wsb + 67108864ull + 393216ull);
  unsigned short* w2t    = (unsigned short*)(wsb + 67108864ull + 917504ull);
  unsigned short* t1b    = (unsigned short*)(wsb + 68550656ull);
  unsigned short* t2b    = (unsigned short*)(wsb + 68550656ull + 25690112ull);
  unsigned short* vb     = (unsigned short*)d_out;
  unsigned short* qb     = (unsigned short*)((char*)d_out + 67108864ull);

  // 0. weight convert + transpose (f32 [K,N] -> bf16 [N,K])
  wconv_kernel<<<dim3(8, 8),  256, 0, stream>>>(wq,    wqt,    CDIM, CDIM);
  wconv_kernel<<<dim3(8, 8),  256, 0, stream>>>(wv,    wvt,    CDIM, CDIM);
  wconv_kernel<<<dim3(8, 8),  256, 0, stream>>>(wproj, wprojt, CDIM, CDIM);
  wconv_kernel<<<dim3(8, 32), 256, 0, stream>>>(w1,    w1t,    CDIM, HIDDIM);
  wconv_kernel<<<dim3(32, 8), 256, 0, stream>>>(w2,    w2t,    HIDDIM, CDIM);

  // 1. LN1: x -> xn (r0)
  ln_kernel<<<32768, 256, 0, stream>>>(x, n1g, n1b, r0);
  // 2-3. q,v projections (bf16 out into d_out halves)
  mgemm<0><<<dim3(1024, 2), 256, 0, stream>>>(r0, wqt, bq, 1.0f, nullptr, qb, CDIM, CDIM);
  mgemm<0><<<dim3(1024, 2), 256, 0, stream>>>(r0, wvt, bv, 1.0f, nullptr, vb, CDIM, CDIM);
  // 4. window attention (k = q) -> yattn (r0; xn dead)
  attn_kernel<<<dim3(2048, NHEAD), 64, 0, stream>>>(qb, vb, rpb, pHo, pWo, r0);
  // 5. xattn = x + yattn@wproj + bproj -> d_out f32 (q/v dead)
  mgemm<1><<<dim3(1024, 2), 256, 0, stream>>>(r0, wprojt, bproj, 1.0f, x, out, CDIM, CDIM);
  // 6. LN2: d_out -> xn2 (r0)
  ln_kernel<<<32768, 256, 0, stream>>>(out, n2g, n2b, r0);
  // 7-9. LeFF over row bands (96,96,64 rows per image x 4 batches):
  //      FF1(full N=1024, +1-row halo) -> dwconv -> FF2(full K=1024, +xattn res)
  for (int bi = 0; bi < BATCH; ++bi) {
    for (int hr0 = 0; hr0 < H_IMG; ) {
      const int br = (H_IMG - hr0 >= 96) ? 96 : (H_IMG - hr0);
      const int r_start = (hr0 > 0) ? hr0 - 1 : 0;
      const int r_end = (hr0 + br <= H_IMG - 1) ? hr0 + br : H_IMG - 1;
      const int nrows = r_end - r_start + 1;
      const unsigned short* Aff1 = r0 + ((size_t)bi * LTOK + (size_t)r_start * W_IMG) * CDIM;
      unsigned short* t1dst = t1b + (size_t)(r_start - hr0 + 1) * W_IMG * HIDDIM;
      mgemm<2><<<dim3(nrows, 8), 256, 0, stream>>>(
          Aff1, w1t, b1, 1.0f, nullptr, t1dst, CDIM, HIDDIM);
      dwconv_kernel<<<dim3(br * 16, 8), 256, 0, stream>>>(t1b, dwk, dwb, t2b, hr0, br);
      const size_t btok = (size_t)bi * LTOK + (size_t)hr0 * W_IMG;
      mgemm<1><<<dim3(br, 2), 256, 0, stream>>>(
          t2b, w2t, b2, 1.0f, out + btok * CDIM, out + btok * CDIM, HIDDIM, CDIM);
      hr0 += br;
    }
  }
}